// Round 9
// baseline (89.536 us; speedup 1.0000x reference)
//
#include <hip/hip_runtime.h>

#define DIM     256
#define NROWS   8192
#define NTILE   64                           // 8192 / 128 tiles per dim
#define NBLK    ((NTILE * (NTILE + 1)) / 2)  // 2080 triangular 128x128 tiles
#define GB      (NBLK * 2)                   // 4160 blocks: one 64x128 half-tile each
#define NPART   (GB * 4)                     // one double2 per wave
#define CHPLANE ((size_t)NROWS * 16)         // chunk-major plane stride in bytes

using i32x4  = __attribute__((ext_vector_type(4))) int;
using i32x8  = __attribute__((ext_vector_type(8))) int;
using f32x16 = __attribute__((ext_vector_type(16))) float;

struct i32x8_pair { i32x4 lo, hi; };

// fp4 e2m1 RNE quantizer for pre-scaled input (representable {0,.5,1,1.5,2,3,4,6})
__device__ __forceinline__ unsigned fp4q(float v) {
  float a = fabsf(v);
  unsigned s = (__builtin_bit_cast(unsigned, v) >> 31) << 3;
  unsigned c = a < 0.25f ? 0u : a < 0.75f ? 1u : a < 1.25f ? 2u : a < 1.75f ? 3u
             : a < 2.50f ? 4u : a < 3.50f ? 5u : a < 5.00f ? 6u : 7u;
  return s | c;
}

// linear triangular tile id -> (bi, bj), bi <= bj
__device__ __forceinline__ void tile_rc(int t, int& bi, int& bj) {
  int i = (int)((129.0 - sqrt(129.0 * 129.0 - 8.0 * (double)t)) * 0.5);
  while ((i * (129 - i)) / 2 > t) --i;
  while (((i + 1) * (128 - i)) / 2 <= t) ++i;
  bi = i;
  bj = i + (t - (i * (129 - i)) / 2);
}

// e^(x/2) = 2^(x * log2(e)/2): one v_mul + one v_exp_f32 (folds the /TEMP)
__device__ __forceinline__ float exp_half(float x) {
  float t = x * 0.7213475204444817f;
  float r;
  asm("v_exp_f32 %0, %1" : "=v"(r) : "v"(t));
  return r;
}

// ---- kernel 1: row-normalize x (fp32) -> z4 (fp4 e2m1, x16 scale), 1 wave/row
// (2048 blocks -- the proven fast shape). z4 is CHUNK-MAJOR: z4[chunk][row],
// 16B per (chunk,row); plane = 128 KB -> gram's gathers are 512B runs.
__global__ __launch_bounds__(256) void normalize_k(const float* __restrict__ x,
                                                   unsigned char* __restrict__ z4) {
  const int row  = blockIdx.x * 4 + (threadIdx.x >> 6);
  const int lane = threadIdx.x & 63;
  float4 v = ((const float4*)(x + (size_t)row * DIM))[lane];
  float ss = v.x * v.x + v.y * v.y + v.z * v.z + v.w * v.w;
#pragma unroll
  for (int off = 32; off > 0; off >>= 1) ss += __shfl_xor(ss, off, 64);
  float rn = rsqrtf(fmaxf(ss, 1e-24f)) * 16.0f;   // pre-apply 2^4 (MX scale 2^-4)
  unsigned c0 = fp4q(v.x * rn), c1 = fp4q(v.y * rn);
  unsigned c2 = fp4q(v.z * rn), c3 = fp4q(v.w * rn);
  // element 2i in low nibble, 2i+1 in high nibble; lane covers elems 4l..4l+3
  unsigned short pk = (unsigned short)((c0 | (c1 << 4)) | ((c2 | (c3 << 4)) << 8));
  *(unsigned short*)(z4 + (size_t)(lane >> 3) * CHPLANE
                        + (size_t)row * 16 + ((2 * lane) & 14)) = pk;
}

// ---- kernel 2: Gram exp-sum, MX-fp4, HALF-TILE blocks for 2x wave concurrency.
// Every prior structure ran at ~8-10 waves/CU and landed at ~17.5 us; this is
// the TLP experiment: 4160 blocks x one 64x128 half-tile, 4 waves in 1x4 grid
// (wave = 64x32 output, acc = 32 f32, ~120 total regs) -> launch_bounds cap 128
// regs -> 16 waves/CU resident. No LDS staging (z4 = 1 MB, L2-resident), no
// barriers; all 12 fragment loads hoisted (one latency epoch); per-LANE f64
// accumulation; one wave-reduce + plain store per wave (no atomics: R1/R7
// showed agent-scope RMW exits cost ~27 us).
__global__ __launch_bounds__(256, 4) void gram_k(const unsigned char* __restrict__ z4,
                                                 double2* __restrict__ partial) {
  const int tid   = threadIdx.x;
  const int lane  = tid & 63;
  const int w     = tid >> 6;               // 1x4 wave grid: col strip w*32
  const int l31   = lane & 31;
  const int khalf = lane >> 5;              // K-half selector for 32x32 frags

  const int h = blockIdx.x & 1;             // which 64-row half of the tile
  int bi, bj; tile_rc(blockIdx.x >> 1, bi, bj);

  // lane base addresses: chunk plane (kc*2 + khalf); A rows = bi*128 + h*64 +
  // rt*32 + l31, B rows = bj*128 + w*32 + l31. 512B-contiguous per 32 lanes.
  const unsigned char* baseA = z4 + (size_t)khalf * CHPLANE
                             + ((size_t)bi * 128 + h * 64 + l31) * 16;
  const unsigned char* baseB = z4 + (size_t)khalf * CHPLANE
                             + ((size_t)bj * 128 + w * 32 + l31) * 16;

  // hoist ALL 12 fragment loads (independent -> single latency epoch)
  i32x4 af[2][4], bf[4];
#pragma unroll
  for (int kc = 0; kc < 4; ++kc) {
    af[0][kc] = *(const i32x4*)(baseA + (size_t)(2 * kc) * CHPLANE);
    af[1][kc] = *(const i32x4*)(baseA + (size_t)(2 * kc) * CHPLANE + 512);
    bf[kc]    = *(const i32x4*)(baseB + (size_t)(2 * kc) * CHPLANE);
  }

  f32x16 acc[2] = {};
  const i32x4 zero4 = {0, 0, 0, 0};
#pragma unroll
  for (int kc = 0; kc < 4; ++kc) {          // four K=64 MFMA chunks
#pragma unroll
    for (int rt = 0; rt < 2; ++rt) {
      i32x8_pair pa = { af[rt][kc], zero4 };  // fp4 reads only low 4 regs
      i32x8_pair pb = { bf[kc],     zero4 };
      acc[rt] = __builtin_amdgcn_mfma_scale_f32_32x32x64_f8f6f4(
          __builtin_bit_cast(i32x8, pa), __builtin_bit_cast(i32x8, pb),
          acc[rt],
          4, 4,                             // FMT: fp4 e2m1 A and B
          0, 0x7B7B7B7B,                    // scale_a = 2^-4 (E8M0 123)
          0, 0x7B7B7B7B);                   // scale_b = 2^-4
    }
  }

  // epilogue: exp(cos/TEMP), TEMP = 2. 4 ILP chains for the 32-deep sum.
  // In-tile coords: row = h*64 + rt*32 + row_l, col = w*32 + l31, where
  // row_l = (r&3) + 8*(r>>2) + 4*khalf (32x32 C/D mapping, col = lane&31).
  // Diagonal element iff (w == 2*h + rt) && (row_l == l31) -- same test for
  // tdiag (bi==bj) and sdiag (bj==bi+32, cols shifted by exactly 4096).
  const bool tdiag = (bi == bj);
  const bool sdiag = (bj == bi + 32);
  float ls[4] = {0.f, 0.f, 0.f, 0.f};
  float dsum = 0.0f;
  if (tdiag || sdiag) {
#pragma unroll
    for (int rt = 0; rt < 2; ++rt)
#pragma unroll
      for (int r = 0; r < 16; ++r) {
        float e = exp_half(acc[rt][r]);
        ls[r & 3] += e;
        int row_l = (r & 3) + 8 * (r >> 2) + 4 * khalf;
        if (w == 2 * h + rt && row_l == l31) dsum += e;
      }
  } else {
#pragma unroll
    for (int rt = 0; rt < 2; ++rt)
#pragma unroll
      for (int r = 0; r < 16; ++r)
        ls[r & 3] += exp_half(acc[rt][r]);
  }
  float lsum = (ls[0] + ls[1]) + (ls[2] + ls[3]);
  // per-LANE contribution (linear in lanes). diag half-tile contributes
  // lsum + diag extra; off-diag counts twice by symmetry.
  double aS = tdiag ? (double)lsum + (double)dsum : 2.0 * (double)lsum;
  double aD = sdiag ? (double)dsum : 0.0;

  // cross-lane f64 reduce within each wave; one plain store per wave.
#pragma unroll
  for (int off = 32; off > 0; off >>= 1) {
    aS += __shfl_xor(aS, off, 64);
    aD += __shfl_xor(aD, off, 64);
  }
  if (lane == 0) {
    double2 v; v.x = aS; v.y = aD;
    partial[blockIdx.x * 4 + w] = v;        // unique slot: no RMW, no init
  }
}

// ---- kernel 3: reduce 16640 partials, compute the loss. One block.
__global__ __launch_bounds__(256) void reduce_k(const double2* __restrict__ partial,
                                               float* __restrict__ out) {
  __shared__ double redS[4], redD[4];
  double s = 0.0, ss = 0.0;
  for (int i = threadIdx.x; i < NPART; i += 256) {
    double2 v = partial[i];
    s += v.x; ss += v.y;
  }
#pragma unroll
  for (int off = 32; off > 0; off >>= 1) {
    s  += __shfl_xor(s,  off, 64);
    ss += __shfl_xor(ss, off, 64);
  }
  const int w = threadIdx.x >> 6;
  if ((threadIdx.x & 63) == 0) { redS[w] = s; redD[w] = ss; }
  __syncthreads();
  if (threadIdx.x == 0) {
    double S  = (redS[0] + redS[1]) + (redS[2] + redS[3]);
    double sd = (redD[0] + redD[1]) + (redD[2] + redD[3]);
    out[0] = (float)(log(0.5 * S + sd) - log(sd));
  }
}

extern "C" void kernel_launch(void* const* d_in, const int* in_sizes, int n_in,
                              void* d_out, int out_size, void* d_ws, size_t ws_size,
                              hipStream_t stream) {
  const float* x    = (const float*)d_in[0];
  unsigned char* z4 = (unsigned char*)d_ws;                  // 8 chunk planes = 1 MB
  double2* partial  = (double2*)((char*)d_ws + 8 * CHPLANE); // 16640*16 B
  float* out        = (float*)d_out;

  normalize_k<<<dim3(NROWS / 4), dim3(256), 0, stream>>>(x, z4);
  gram_k<<<dim3(GB), dim3(256), 0, stream>>>(z4, partial);
  reduce_k<<<dim3(1), dim3(256), 0, stream>>>(partial, out);
}

// Round 10
// 82.200 us; speedup vs baseline: 1.0892x; 1.0892x over previous
//
#include <hip/hip_runtime.h>

#define DIM     256
#define NROWS   8192
#define NTILE   64                           // 8192 / 128 tiles per dim
#define NBLK    ((NTILE * (NTILE + 1)) / 2)  // 2080 triangular tiles
#define GB      1040                         // gram blocks (2 tiles each)
#define NPART   (GB * 4)                     // one double2 per wave
#define CHPLANE ((size_t)NROWS * 16)         // chunk-major plane stride in bytes

using i32x4  = __attribute__((ext_vector_type(4))) int;
using i32x8  = __attribute__((ext_vector_type(8))) int;
using f32x16 = __attribute__((ext_vector_type(16))) float;

struct i32x8_pair { i32x4 lo, hi; };

// fp4 e2m1 RNE quantizer for pre-scaled input (representable {0,.5,1,1.5,2,3,4,6})
__device__ __forceinline__ unsigned fp4q(float v) {
  float a = fabsf(v);
  unsigned s = (__builtin_bit_cast(unsigned, v) >> 31) << 3;
  unsigned c = a < 0.25f ? 0u : a < 0.75f ? 1u : a < 1.25f ? 2u : a < 1.75f ? 3u
             : a < 2.50f ? 4u : a < 3.50f ? 5u : a < 5.00f ? 6u : 7u;
  return s | c;
}

// linear triangular tile id -> (bi, bj), bi <= bj
__device__ __forceinline__ void tile_rc(int t, int& bi, int& bj) {
  int i = (int)((129.0 - sqrt(129.0 * 129.0 - 8.0 * (double)t)) * 0.5);
  while ((i * (129 - i)) / 2 > t) --i;
  while (((i + 1) * (128 - i)) / 2 <= t) ++i;
  bi = i;
  bj = i + (t - (i * (129 - i)) / 2);
}

// e^(x/2) = 2^(x * log2(e)/2): one v_mul + one v_exp_f32 (folds the /TEMP)
__device__ __forceinline__ float exp_half(float x) {
  float t = x * 0.7213475204444817f;
  float r;
  asm("v_exp_f32 %0, %1" : "=v"(r) : "v"(t));
  return r;
}

// ---- kernel 1: row-normalize x (fp32) -> z4 (fp4 e2m1, x16 scale).
// 256 blocks; each wave loops 8 rows.
// z4 is CHUNK-MAJOR: z4[chunk][row], 16B per (chunk,row); plane = 128 KB.
__global__ __launch_bounds__(256) void normalize_k(const float* __restrict__ x,
                                                   unsigned char* __restrict__ z4) {
  const int w    = threadIdx.x >> 6;
  const int lane = threadIdx.x & 63;
  const int row0 = blockIdx.x * 32 + w * 8;
#pragma unroll
  for (int r = 0; r < 8; ++r) {
    const int row = row0 + r;
    float4 v = ((const float4*)(x + (size_t)row * DIM))[lane];
    float ss = v.x * v.x + v.y * v.y + v.z * v.z + v.w * v.w;
#pragma unroll
    for (int off = 32; off > 0; off >>= 1) ss += __shfl_xor(ss, off, 64);
    float rn = rsqrtf(fmaxf(ss, 1e-24f)) * 16.0f; // pre-apply 2^4 (MX scale 2^-4)
    unsigned c0 = fp4q(v.x * rn), c1 = fp4q(v.y * rn);
    unsigned c2 = fp4q(v.z * rn), c3 = fp4q(v.w * rn);
    // elem 2i low nibble, 2i+1 high; lane covers elems 4l..4l+3
    unsigned short pk = (unsigned short)((c0 | (c1 << 4)) | ((c2 | (c3 << 4)) << 8));
    *(unsigned short*)(z4 + (size_t)(lane >> 3) * CHPLANE
                          + (size_t)row * 16 + ((2 * lane) & 14)) = pk;
  }
}

// ---- kernel 2: Gram exp-sum over upper-triangular 128x128 tiles, MX-fp4.
// 1040 blocks x 2 tiles. NO LDS staging (z4 = 1 MB is L2-resident), NO
// barriers: each lane loads its MFMA fragments (16B = one 32-elem K-chunk of
// one row) straight from global (chunk-major -> two contiguous 512B segments
// per instruction). Waves fully independent; per-LANE f64 accumulation across
// both tiles; one plain store per wave at exit (no atomics/fences: R1/R7
// showed agent-scope RMW exits cost ~27 us on non-coherent per-XCD L2s).
__global__ __launch_bounds__(256, 3) void gram_k(const unsigned char* __restrict__ z4,
                                                 double2* __restrict__ partial) {
  const int tid   = threadIdx.x;
  const int lane  = tid & 63;
  const int w     = tid >> 6;
  const int wr    = w >> 1, wc = w & 1;     // 2x2 wave grid, 64x64 each
  const int l31   = lane & 31;
  const int khalf = lane >> 5;              // K-half selector for 32x32 frags

  double accS = 0.0, accD = 0.0;
  const i32x4 zero4 = {0, 0, 0, 0};

  for (int k = 0; k < 2; ++k) {
    int bi, bj; tile_rc(blockIdx.x * 2 + k, bi, bj);

    // lane base addresses: chunk plane (kc*2 + khalf), row = tile_row0 + sub
    const unsigned char* baseA = z4 + (size_t)khalf * CHPLANE
                               + ((size_t)bi * 128 + wr * 64 + l31) * 16;
    const unsigned char* baseB = z4 + (size_t)khalf * CHPLANE
                               + ((size_t)bj * 128 + wc * 64 + l31) * 16;

    f32x16 acc_f[2][2] = {};
#pragma unroll
    for (int kc = 0; kc < 4; ++kc) {        // four K=64 MFMA chunks
      i32x8 a[2], b[2];
#pragma unroll
      for (int t = 0; t < 2; ++t) {
        i32x8_pair pa = { *(const i32x4*)(baseA + (size_t)(2 * kc) * CHPLANE + t * 512),
                          zero4 };
        a[t] = __builtin_bit_cast(i32x8, pa); // fp4 reads only low 4 regs
        i32x8_pair pb = { *(const i32x4*)(baseB + (size_t)(2 * kc) * CHPLANE + t * 512),
                          zero4 };
        b[t] = __builtin_bit_cast(i32x8, pb);
      }
#pragma unroll
      for (int ti = 0; ti < 2; ++ti)
#pragma unroll
        for (int tj = 0; tj < 2; ++tj)
          acc_f[ti][tj] = __builtin_amdgcn_mfma_scale_f32_32x32x64_f8f6f4(
              a[ti], b[tj], acc_f[ti][tj],
              4, 4,                         // FMT: fp4 e2m1 A and B
              0, 0x7B7B7B7B,                // scale_a = 2^-4 (E8M0 123)
              0, 0x7B7B7B7B);               // scale_b = 2^-4
    }

    // epilogue: exp(cos/TEMP), TEMP = 2. 4 ILP chains for the 64-deep sum.
    const bool tdiag = (bi == bj);          // true diagonal tile
    const bool sdiag = (bj == bi + 32);     // (i, i+4096) sim_s tile
    float ls[4] = {0.f, 0.f, 0.f, 0.f};
    float dsum = 0.0f;
    if (tdiag || sdiag) {
#pragma unroll
      for (int ti = 0; ti < 2; ++ti)
#pragma unroll
        for (int tj = 0; tj < 2; ++tj)
#pragma unroll
          for (int r = 0; r < 16; ++r) {
            float e = exp_half(acc_f[ti][tj][r]);
            ls[r & 3] += e;
            // 32x32 C/D: col = lane&31, row = (reg&3) + 8*(reg>>2) + 4*khalf
            int row_l = (r & 3) + 8 * (r >> 2) + 4 * khalf;
            if (wr == wc && ti == tj && row_l == l31) dsum += e;
          }
    } else {
#pragma unroll
      for (int ti = 0; ti < 2; ++ti)
#pragma unroll
        for (int tj = 0; tj < 2; ++tj)
#pragma unroll
          for (int r = 0; r < 16; ++r)
            ls[r & 3] += exp_half(acc_f[ti][tj][r]);
    }
    float lsum = (ls[0] + ls[1]) + (ls[2] + ls[3]);
    // per-LANE tile contribution (linear in lanes: summing later gives tile
    // totals). diag tile contributes lsum + diag extra; off-diag counts twice.
    accS += tdiag ? (double)lsum + (double)dsum : 2.0 * (double)lsum;
    if (sdiag) accD += (double)dsum;
  }

  // cross-lane f64 reduce within each wave; one plain store per wave.
#pragma unroll
  for (int off = 32; off > 0; off >>= 1) {
    accS += __shfl_xor(accS, off, 64);
    accD += __shfl_xor(accD, off, 64);
  }
  if (lane == 0) {
    double2 v; v.x = accS; v.y = accD;
    partial[blockIdx.x * 4 + w] = v;        // unique slot: no RMW, no init
  }
}

// ---- kernel 3: reduce 4160 partials, compute the loss. One block.
__global__ __launch_bounds__(256) void reduce_k(const double2* __restrict__ partial,
                                               float* __restrict__ out) {
  __shared__ double redS[4], redD[4];
  double s = 0.0, ss = 0.0;
  for (int i = threadIdx.x; i < NPART; i += 256) {
    double2 v = partial[i];
    s += v.x; ss += v.y;
  }
#pragma unroll
  for (int off = 32; off > 0; off >>= 1) {
    s  += __shfl_xor(s,  off, 64);
    ss += __shfl_xor(ss, off, 64);
  }
  const int w = threadIdx.x >> 6;
  if ((threadIdx.x & 63) == 0) { redS[w] = s; redD[w] = ss; }
  __syncthreads();
  if (threadIdx.x == 0) {
    double S  = redS[0] + redS[1] + redS[2] + redS[3];
    double sd = redD[0] + redD[1] + redD[2] + redD[3];
    out[0] = (float)(log(0.5 * S + sd) - log(sd));
  }
}

extern "C" void kernel_launch(void* const* d_in, const int* in_sizes, int n_in,
                              void* d_out, int out_size, void* d_ws, size_t ws_size,
                              hipStream_t stream) {
  const float* x    = (const float*)d_in[0];
  unsigned char* z4 = (unsigned char*)d_ws;                  // 8 chunk planes = 1 MB
  double2* partial  = (double2*)((char*)d_ws + 8 * CHPLANE); // 4160*16 B
  float* out        = (float*)d_out;

  normalize_k<<<dim3(256),  dim3(256), 0, stream>>>(x, z4);
  gram_k<<<dim3(GB),        dim3(256), 0, stream>>>(z4, partial);
  reduce_k<<<dim3(1),       dim3(256), 0, stream>>>(partial, out);
}

// Round 11
// 74.285 us; speedup vs baseline: 1.2053x; 1.1066x over previous
//
#include <hip/hip_runtime.h>

#define DIM     256
#define NROWS   8192
#define NTILE   64                           // 8192 / 128 tiles per dim
#define NBLK    ((NTILE * (NTILE + 1)) / 2)  // 2080 triangular tiles
#define CHPLANE ((size_t)NROWS * 16)         // chunk-major plane stride in bytes

using i32x4  = __attribute__((ext_vector_type(4))) int;
using i32x8  = __attribute__((ext_vector_type(8))) int;
using f32x16 = __attribute__((ext_vector_type(16))) float;

struct i32x8_pair { i32x4 lo, hi; };

// fp4 e2m1 RNE quantizer for pre-scaled input (representable {0,.5,1,1.5,2,3,4,6})
__device__ __forceinline__ unsigned fp4q(float v) {
  float a = fabsf(v);
  unsigned s = (__builtin_bit_cast(unsigned, v) >> 31) << 3;
  unsigned c = a < 0.25f ? 0u : a < 0.75f ? 1u : a < 1.25f ? 2u : a < 1.75f ? 3u
             : a < 2.50f ? 4u : a < 3.50f ? 5u : a < 5.00f ? 6u : 7u;
  return s | c;
}

// linear triangular tile id -> (bi, bj), bi <= bj
__device__ __forceinline__ void tile_rc(int t, int& bi, int& bj) {
  int i = (int)((129.0 - sqrt(129.0 * 129.0 - 8.0 * (double)t)) * 0.5);
  while ((i * (129 - i)) / 2 > t) --i;
  while (((i + 1) * (128 - i)) / 2 <= t) ++i;
  bi = i;
  bj = i + (t - (i * (129 - i)) / 2);
}

// e^(x/2) = 2^(x * log2(e)/2): one v_mul + one v_exp_f32 (folds the /TEMP)
__device__ __forceinline__ float exp_half(float x) {
  float t = x * 0.7213475204444817f;
  float r;
  asm("v_exp_f32 %0, %1" : "=v"(r) : "v"(t));
  return r;
}

// ---- kernel 1: row-normalize x (fp32) -> z4 (fp4 e2m1, x16 scale), 1 wave/row.
// z4 is CHUNK-MAJOR: z4[chunk][row] with 16B per (chunk,row); plane = 128 KB.
// This makes gram's per-lane fragment gathers perfectly coalesced (512B runs).
__global__ __launch_bounds__(256) void normalize_k(const float* __restrict__ x,
                                                   unsigned char* __restrict__ z4) {
  const int row  = blockIdx.x * 4 + (threadIdx.x >> 6);
  const int lane = threadIdx.x & 63;
  float4 v = ((const float4*)(x + (size_t)row * DIM))[lane];
  float ss = v.x * v.x + v.y * v.y + v.z * v.z + v.w * v.w;
#pragma unroll
  for (int off = 32; off > 0; off >>= 1) ss += __shfl_xor(ss, off, 64);
  float rn = rsqrtf(fmaxf(ss, 1e-24f)) * 16.0f;   // pre-apply 2^4 (MX scale 2^-4)
  unsigned c0 = fp4q(v.x * rn), c1 = fp4q(v.y * rn);
  unsigned c2 = fp4q(v.z * rn), c3 = fp4q(v.w * rn);
  // element 2i in low nibble, 2i+1 in high nibble; lane covers elems 4l..4l+3
  unsigned short pk = (unsigned short)((c0 | (c1 << 4)) | ((c2 | (c3 << 4)) << 8));
  // lane's 2 bytes land in chunk (lane>>3), byte-in-chunk (2*lane)&15
  *(unsigned short*)(z4 + (size_t)(lane >> 3) * CHPLANE
                        + (size_t)row * 16 + ((2 * lane) & 14)) = pk;
}

// ---- kernel 2: Gram exp-sum over upper-triangular 128x128 tiles, MX-fp4.
// NO LDS staging (z4 = 1 MB is L2-resident; staging was pure overhead): each
// lane loads its MFMA fragments (16B = one 32-elem K-chunk of one row)
// directly from global. Chunk-major layout -> every load is two contiguous
// 512B segments. No barriers in the hot path; waves fully independent;
// latency hidden by TLP (3 waves/SIMD, VGPR-bound).
__global__ __launch_bounds__(256, 3) void gram_k(const unsigned char* __restrict__ z4,
                                                 double2* __restrict__ partial) {
  __shared__ float red[8];

  const int tid   = threadIdx.x;
  const int lane  = tid & 63;
  const int w     = tid >> 6;
  const int wr    = w >> 1, wc = w & 1;     // 2x2 wave grid, 64x64 each
  const int l31   = lane & 31;
  const int khalf = lane >> 5;              // K-half selector for 32x32 frags

  int bi, bj; tile_rc(blockIdx.x, bi, bj);

  // lane base addresses: chunk plane (kc*2 + khalf), row = tile_row0 + sub
  const unsigned char* baseA = z4 + (size_t)khalf * CHPLANE
                             + ((size_t)bi * 128 + wr * 64 + l31) * 16;
  const unsigned char* baseB = z4 + (size_t)khalf * CHPLANE
                             + ((size_t)bj * 128 + wc * 64 + l31) * 16;

  f32x16 acc_f[2][2] = {};
  const i32x4 zero4 = {0, 0, 0, 0};
#pragma unroll
  for (int kc = 0; kc < 4; ++kc) {          // four K=64 MFMA chunks
    i32x8 a[2], b[2];
#pragma unroll
    for (int t = 0; t < 2; ++t) {
      i32x8_pair pa = { *(const i32x4*)(baseA + (size_t)(2 * kc) * CHPLANE + t * 32 * 16),
                        zero4 };
      a[t] = __builtin_bit_cast(i32x8, pa); // fp4 reads only low 4 regs
      i32x8_pair pb = { *(const i32x4*)(baseB + (size_t)(2 * kc) * CHPLANE + t * 32 * 16),
                        zero4 };
      b[t] = __builtin_bit_cast(i32x8, pb);
    }
#pragma unroll
    for (int ti = 0; ti < 2; ++ti)
#pragma unroll
      for (int tj = 0; tj < 2; ++tj)
        acc_f[ti][tj] = __builtin_amdgcn_mfma_scale_f32_32x32x64_f8f6f4(
            a[ti], b[tj], acc_f[ti][tj],
            4, 4,                           // FMT: fp4 e2m1 A and B
            0, 0x7B7B7B7B,                  // scale_a = 2^-4 (E8M0 123)
            0, 0x7B7B7B7B);                 // scale_b = 2^-4
  }

  // epilogue: exp(cos/TEMP), TEMP = 2. Uniform-branch diagonal handling.
  const bool tdiag = (bi == bj);            // true diagonal tile
  const bool sdiag = (bj == bi + 32);       // (i, i+4096) sim_s tile
  float lsum = 0.0f, dsum = 0.0f;
  if (tdiag || sdiag) {
#pragma unroll
    for (int ti = 0; ti < 2; ++ti)
#pragma unroll
      for (int tj = 0; tj < 2; ++tj)
#pragma unroll
        for (int r = 0; r < 16; ++r) {
          float e = exp_half(acc_f[ti][tj][r]);
          lsum += e;
          // 32x32 C/D: col = lane&31, row = (reg&3) + 8*(reg>>2) + 4*khalf
          int row_l = (r & 3) + 8 * (r >> 2) + 4 * khalf;
          if (wr == wc && ti == tj && row_l == l31) dsum += e;
        }
  } else {
#pragma unroll
    for (int ti = 0; ti < 2; ++ti)
#pragma unroll
      for (int tj = 0; tj < 2; ++tj)
#pragma unroll
        for (int r = 0; r < 16; ++r)
          lsum += exp_half(acc_f[ti][tj][r]);
  }
#pragma unroll
  for (int off = 32; off > 0; off >>= 1) lsum += __shfl_xor(lsum, off, 64);
  if (tdiag || sdiag) {
#pragma unroll
    for (int off = 32; off > 0; off >>= 1) dsum += __shfl_xor(dsum, off, 64);
  }
  if (lane == 0) { red[w] = lsum; red[4 + w] = dsum; }
  __syncthreads();                          // only barrier: final combine

  if (tid == 0) {
    float l  = red[0] + red[1] + red[2] + red[3];
    float dd = red[4] + red[5] + red[6] + red[7];
    // diag tile contributes lsum + diag extra; off-diag counts twice (symmetry)
    double2 v;
    v.x = tdiag ? (double)l + (double)dd : 2.0 * (double)l;
    v.y = sdiag ? (double)dd : 0.0;
    partial[blockIdx.x] = v;                // unique slot: plain store, no RMW
  }
}

// ---- kernel 3: reduce 2080 partials, compute the loss. One block.
__global__ __launch_bounds__(256) void reduce_k(const double2* __restrict__ partial,
                                               float* __restrict__ out) {
  __shared__ double redS[4], redD[4];
  double s = 0.0, ss = 0.0;
  for (int i = threadIdx.x; i < NBLK; i += 256) {
    double2 v = partial[i];
    s += v.x; ss += v.y;
  }
#pragma unroll
  for (int off = 32; off > 0; off >>= 1) {
    s  += __shfl_xor(s,  off, 64);
    ss += __shfl_xor(ss, off, 64);
  }
  const int w = threadIdx.x >> 6;
  if ((threadIdx.x & 63) == 0) { redS[w] = s; redD[w] = ss; }
  __syncthreads();
  if (threadIdx.x == 0) {
    double S  = redS[0] + redS[1] + redS[2] + redS[3];
    double sd = redD[0] + redD[1] + redD[2] + redD[3];
    out[0] = (float)(log(0.5 * S + sd) - log(sd));
  }
}

extern "C" void kernel_launch(void* const* d_in, const int* in_sizes, int n_in,
                              void* d_out, int out_size, void* d_ws, size_t ws_size,
                              hipStream_t stream) {
  const float* x    = (const float*)d_in[0];
  unsigned char* z4 = (unsigned char*)d_ws;                  // 8 chunk planes = 1 MB
  double2* partial  = (double2*)((char*)d_ws + 8 * CHPLANE); // 2080*16 B
  float* out        = (float*)d_out;

  normalize_k<<<dim3(NROWS / 4), dim3(256), 0, stream>>>(x, z4);
  gram_k<<<dim3(NBLK), dim3(256), 0, stream>>>(z4, partial);
  reduce_k<<<dim3(1), dim3(256), 0, stream>>>(partial, out);
}